// Round 4
// baseline (501.280 us; speedup 1.0000x reference)
//
#include <hip/hip_runtime.h>
#include <hip/hip_bf16.h>

#define N_NODES 16384
#define KDIM    16384
#define HID     64
#define N_EDGES 524288
#define KSPLIT  4
#define KC      (KDIM / KSPLIT)   /* 4096 */
#define BK      64
#define NT      (KC / BK)         /* 64 K-steps per block */

typedef __bf16 bf16x8 __attribute__((ext_vector_type(8)));
typedef float  f32x4  __attribute__((ext_vector_type(4)));

__device__ __forceinline__ unsigned cvt_pk(float a, float b) {
    unsigned r;
    asm("v_cvt_pk_bf16_f32 %0, %1, %2" : "=v"(r) : "v"(a), "v"(b));
    return r;
}

// ---- W1 [K][64] f32  ->  W1t packed [64][K/2] u32 (2 bf16 per u32, pair = (2k, 2k+1))
__global__ void pack_w1t(const float* __restrict__ W1, unsigned* __restrict__ W1t) {
    int tid = blockIdx.x * 256 + threadIdx.x;
    int c  = tid & 63;
    int kp = tid >> 6;
    float f0 = W1[(size_t)(2 * kp)     * HID + c];
    float f1 = W1[(size_t)(2 * kp + 1) * HID + c];
    W1t[(size_t)c * (KDIM / 2) + kp] = cvt_pk(f0, f1);
}

__global__ void deg_acc(const int* __restrict__ ei, const float* __restrict__ w,
                        float* deg) {
    int e = blockIdx.x * 256 + threadIdx.x;
    atomicAdd(&deg[ei[N_EDGES + e]], w[e]);
}

// deg was zeroed by memset; self-loop weight 1 folded in here
__global__ void dinv_k(const float* __restrict__ deg, float* __restrict__ dinv) {
    int i = blockIdx.x * 256 + threadIdx.x;
    dinv[i] = rsqrtf(deg[i] + 1.0f);
}

// ---- hpre = x @ W1 : bf16 MFMA, f32 accum, K-split, depth-2 ping-pong pipeline
__global__ __launch_bounds__(256, 4) void gemm1(const float* __restrict__ x,
                                                const unsigned* __restrict__ w1t,
                                                float* __restrict__ hpre) {
    // swizzled LDS tiles: row stride 128B = 8 slots of 16B; slot ^= (row&7)
    __shared__ unsigned As_u[2][64 * 32];
    __shared__ unsigned Bs_u[2][64 * 32];

    const int t    = threadIdx.x;
    const int wave = t >> 6;
    const int lane = t & 63;
    const int row0 = blockIdx.x * 64;
    const int k00  = blockIdx.y * KC;

    const int a_row  = t >> 4;        // 0..15 (i*16 added)
    const int a_fq   = t & 15;        // float4 index in row
    const int a_slot = a_fq >> 1, a_half = a_fq & 1;
    const int fr_lo  = lane & 15, fr_hi = lane >> 4;
    const int b_c    = t >> 3;        // B stage: col (i*32 added)
    const int b_slot = t & 7;

    float4 paA[4], paB[4];
    uint4  pbA[2], pbB[2];

    f32x4 acc[4] = {{0.f,0.f,0.f,0.f},{0.f,0.f,0.f,0.f},{0.f,0.f,0.f,0.f},{0.f,0.f,0.f,0.f}};

#define ISSUE(pa, pb, k0) do {                                                      \
    _Pragma("unroll") for (int i = 0; i < 4; ++i) {                                 \
        int row = a_row + i * 16;                                                   \
        pa[i] = *(const float4*)(x + (size_t)(row0 + row) * KDIM + (k0) + a_fq * 4);\
    }                                                                               \
    _Pragma("unroll") for (int i = 0; i < 2; ++i) {                                 \
        int c = b_c + i * 32;                                                       \
        pb[i] = *(const uint4*)(w1t + (size_t)c * (KDIM / 2) + ((k0) >> 1) + b_slot * 4); \
    } } while (0)

#define WRITE(pa, pb, buf) do {                                                     \
    _Pragma("unroll") for (int i = 0; i < 4; ++i) {                                 \
        int row = a_row + i * 16;                                                   \
        unsigned u0 = cvt_pk(pa[i].x, pa[i].y), u1 = cvt_pk(pa[i].z, pa[i].w);      \
        unsigned* dst = &As_u[buf][row * 32 + ((a_slot ^ (row & 7)) << 2) + a_half * 2]; \
        dst[0] = u0; dst[1] = u1;                                                   \
    }                                                                               \
    _Pragma("unroll") for (int i = 0; i < 2; ++i) {                                 \
        int c = b_c + i * 32;                                                       \
        *(uint4*)&Bs_u[buf][c * 32 + ((b_slot ^ (c & 7)) << 2)] = pb[i];            \
    } } while (0)

#define MFMA_STEP(buf) do {                                                         \
    _Pragma("unroll") for (int kk = 0; kk < 2; ++kk) {                              \
        int slot = kk * 4 + fr_hi;                                                  \
        int ar = wave * 16 + fr_lo;                                                 \
        bf16x8 a = *(const bf16x8*)&As_u[buf][ar * 32 + ((slot ^ (ar & 7)) << 2)];  \
        _Pragma("unroll") for (int ct = 0; ct < 4; ++ct) {                          \
            int bc = ct * 16 + fr_lo;                                               \
            bf16x8 b = *(const bf16x8*)&Bs_u[buf][bc * 32 + ((slot ^ (bc & 7)) << 2)]; \
            acc[ct] = __builtin_amdgcn_mfma_f32_16x16x32_bf16(a, b, acc[ct], 0, 0, 0); \
        } } } while (0)

    // ---- prologue: regsA <- tile0, regsB <- tile1, write tile0, barrier
    ISSUE(paA, pbA, k00);
    ISSUE(paB, pbB, k00 + BK);
    WRITE(paA, pbA, 0);
    __syncthreads();

    // invariant at loop top: buf0 = tile tt, regsB = tile tt+1 (arrived), regsA free
    #pragma unroll 1
    for (int tt = 0; tt < NT - 2; tt += 2) {
        ISSUE(paA, pbA, k00 + (tt + 2) * BK);   // tile tt+2 -> regsA
        MFMA_STEP(0);                           // compute tile tt
        WRITE(paB, pbB, 1);                     // tile tt+1 (loaded last iter: no stall)
        __syncthreads();
        ISSUE(paB, pbB, k00 + (tt + 3) * BK);   // tile tt+3 -> regsB
        MFMA_STEP(1);                           // compute tile tt+1
        WRITE(paA, pbA, 0);                     // tile tt+2
        __syncthreads();
    }
    // epilogue: buf0 = tile NT-2, regsB = tile NT-1
    MFMA_STEP(0);
    WRITE(paB, pbB, 1);
    __syncthreads();
    MFMA_STEP(1);

#undef ISSUE
#undef WRITE
#undef MFMA_STEP

    // C layout (m89): col = lane&15, row = (lane>>4)*4 + reg
    #pragma unroll
    for (int ct = 0; ct < 4; ++ct) {
        int c = ct * 16 + fr_lo;
        #pragma unroll
        for (int r = 0; r < 4; ++r) {
            int row = wave * 16 + fr_hi * 4 + r;
            atomicAdd(&hpre[(size_t)(row0 + row) * HID + c], acc[ct][r]);
        }
    }
}

// ---- layer-1 aggregation: one wave per edge, lane = column
__global__ void agg1_k(const int* __restrict__ ei, const float* __restrict__ w,
                       const float* __restrict__ dinv, const float* __restrict__ hpre,
                       float* __restrict__ agg1) {
    int e    = (blockIdx.x * 256 + threadIdx.x) >> 6;
    int lane = threadIdx.x & 63;
    int s = ei[e];
    int d = ei[N_EDGES + e];
    float wn = dinv[s] * w[e] * dinv[d];
    atomicAdd(&agg1[(size_t)d * HID + lane], wn * hpre[(size_t)s * HID + lane]);
}

// ---- finalize layer 1 (+ self loop + bias + relu) fused with h @ W2 -> s
__global__ void fin1_k(const float* __restrict__ agg1, const float* __restrict__ hpre,
                       const float* __restrict__ dinv, const float* __restrict__ b1,
                       const float* __restrict__ W2, float* __restrict__ s_out) {
    int i = (blockIdx.x * 256 + threadIdx.x) >> 6;
    int c = threadIdx.x & 63;
    float self = dinv[i] * dinv[i];
    float v = agg1[(size_t)i * HID + c] + self * hpre[(size_t)i * HID + c] + b1[c];
    v = fmaxf(v, 0.0f);
    float tv = v * W2[c];
    #pragma unroll
    for (int off = 32; off > 0; off >>= 1) tv += __shfl_xor(tv, off);
    if (c == 0) s_out[i] = tv;
}

// ---- layer-2 aggregation: scalar per edge
__global__ void agg2_k(const int* __restrict__ ei, const float* __restrict__ w,
                       const float* __restrict__ dinv, const float* __restrict__ s,
                       float* __restrict__ out_acc) {
    int e = blockIdx.x * 256 + threadIdx.x;
    int sr = ei[e];
    int d  = ei[N_EDGES + e];
    atomicAdd(&out_acc[d], dinv[sr] * w[e] * dinv[d] * s[sr]);
}

__global__ void fin2_k(const float* __restrict__ out_acc, const float* __restrict__ dinv,
                       const float* __restrict__ s, const float* __restrict__ b2,
                       float* __restrict__ out) {
    int i = blockIdx.x * 256 + threadIdx.x;
    out[i] = out_acc[i] + dinv[i] * dinv[i] * s[i] + b2[0];
}

extern "C" void kernel_launch(void* const* d_in, const int* in_sizes, int n_in,
                              void* d_out, int out_size, void* d_ws, size_t ws_size,
                              hipStream_t stream) {
    const float* x  = (const float*)d_in[0];
    const int*   ei = (const int*)d_in[1];      // int32 (harness delivers integers as int)
    const float* ew = (const float*)d_in[2];
    const float* W1 = (const float*)d_in[3];
    const float* b1 = (const float*)d_in[4];
    const float* W2 = (const float*)d_in[5];
    const float* b2 = (const float*)d_in[6];
    float* out = (float*)d_out;

    char* ws = (char*)d_ws;
    unsigned* w1t    = (unsigned*)(ws);                          // 2 MiB
    float*    hpre   = (float*)(ws + (2u << 20));                // 4 MiB
    float*    agg1   = (float*)(ws + (6u << 20));                // 4 MiB
    float*    outacc = (float*)(ws + (10u << 20));               // 64 KiB
    float*    deg    = (float*)(ws + (10u << 20) + (64u << 10)); // 64 KiB
    float*    dinv   = (float*)(ws + (10u << 20) + (128u << 10));
    float*    s      = (float*)(ws + (10u << 20) + (192u << 10));

    // zero hpre + agg1 + outacc + deg (contiguous region)
    hipMemsetAsync(ws + (2u << 20), 0, (8u << 20) + (128u << 10), stream);

    pack_w1t<<<(64 * (KDIM / 2)) / 256, 256, 0, stream>>>(W1, w1t);
    deg_acc<<<N_EDGES / 256, 256, 0, stream>>>(ei, ew, deg);
    dinv_k<<<N_NODES / 256, 256, 0, stream>>>(deg, dinv);
    gemm1<<<dim3(N_NODES / 64, KSPLIT), 256, 0, stream>>>(x, w1t, hpre);
    agg1_k<<<(N_EDGES * 64) / 256, 256, 0, stream>>>(ei, ew, dinv, hpre, agg1);
    fin1_k<<<N_NODES / 4, 256, 0, stream>>>(agg1, hpre, dinv, b1, W2, s);
    agg2_k<<<N_EDGES / 256, 256, 0, stream>>>(ei, ew, dinv, s, outacc);
    fin2_k<<<N_NODES / 256, 256, 0, stream>>>(outacc, dinv, s, b2, out);
}

// Round 5
// 391.453 us; speedup vs baseline: 1.2806x; 1.2806x over previous
//
#include <hip/hip_runtime.h>
#include <hip/hip_bf16.h>

#define N_NODES 16384
#define KDIM    16384
#define HID     64
#define N_EDGES 524288
#define BK      64

typedef __bf16 bf16x8 __attribute__((ext_vector_type(8)));
typedef float  f32x4  __attribute__((ext_vector_type(4)));
typedef unsigned uint32x4 __attribute__((ext_vector_type(4)));

__device__ __forceinline__ unsigned cvt_pk(float a, float b) {
    unsigned r;
    asm("v_cvt_pk_bf16_f32 %0, %1, %2" : "=v"(r) : "v"(a), "v"(b));
    return r;
}

__device__ __forceinline__ void gload16(const void* g, void* l) {
    __builtin_amdgcn_global_load_lds(
        (const __attribute__((address_space(1))) unsigned*)g,
        (__attribute__((address_space(3))) unsigned*)l,
        16, 0, 0);
}

// ---- W1 [K][64] f32  ->  W1t packed [64][K/2] u32 (2 bf16 per u32, pair = (2k, 2k+1))
__global__ void pack_w1t(const float* __restrict__ W1, unsigned* __restrict__ W1t) {
    int tid = blockIdx.x * 256 + threadIdx.x;
    int c  = tid & 63;
    int kp = tid >> 6;
    float f0 = W1[(size_t)(2 * kp)     * HID + c];
    float f1 = W1[(size_t)(2 * kp + 1) * HID + c];
    W1t[(size_t)c * (KDIM / 2) + kp] = cvt_pk(f0, f1);
}

__global__ void deg_acc(const int* __restrict__ ei, const float* __restrict__ w,
                        float* deg) {
    int e = blockIdx.x * 256 + threadIdx.x;
    atomicAdd(&deg[ei[N_EDGES + e]], w[e]);
}

// deg was zeroed by memset; self-loop weight 1 folded in here
__global__ void dinv_k(const float* __restrict__ deg, float* __restrict__ dinv) {
    int i = blockIdx.x * 256 + threadIdx.x;
    dinv[i] = rsqrtf(deg[i] + 1.0f);
}

// ---- hpre = x @ W1 : A staged f32 via global_load_lds (linear dest, inverse-
// swizzled source), cvt to bf16 at fragment read; B staged bf16 the same way.
// True LDS double-buffer, one barrier per K-step. K split 3 ways (86/86/84).
__global__ __launch_bounds__(256, 3) void gemm1(const float* __restrict__ x,
                                                const unsigned* __restrict__ w1t,
                                                float* __restrict__ hpre) {
    __shared__ unsigned As_u[2][64 * 64];   // f32 tile as u32; 16 KB per buf
    __shared__ unsigned Bs_u[2][64 * 32];   // packed bf16 tile; 8 KB per buf

    const int t    = threadIdx.x;
    const int wave = t >> 6;
    const int lane = t & 63;
    const int row0 = blockIdx.x * 64;
    const int y    = blockIdx.y;
    const int k00  = y * 5504;              // 86*64; y=2 ends at 11008+84*64=16384
    const int NTb  = (y < 2) ? 86 : 84;
    const int fr_lo = lane & 15, fr_hi = lane >> 4;
    const int ar    = wave * 16 + fr_lo;

    // Per-lane global staging pointers. Source is inverse-swizzled so the
    // linear LDS write lands data at phys slot s_phys = s_log ^ (row&15) [A]
    // / s_log ^ (col&7) [B]. Permutation stays inside one row segment ->
    // coalescing preserved.
    const float* pA[4];
    #pragma unroll
    for (int i = 0; i < 4; ++i) {
        int row = (wave * 4 + i) * 4 + (lane >> 4);
        int col = ((lane & 15) ^ (row & 15)) * 4;
        pA[i] = x + (size_t)(row0 + row) * KDIM + k00 + col;
    }
    const unsigned* pB[2];
    #pragma unroll
    for (int i = 0; i < 2; ++i) {
        int c = (wave * 2 + i) * 8 + (lane >> 3);
        int s = ((lane & 7) ^ (c & 7)) * 4;
        pB[i] = w1t + (size_t)c * (KDIM / 2) + (k00 >> 1) + s;
    }

    f32x4 acc[4] = {{0.f,0.f,0.f,0.f},{0.f,0.f,0.f,0.f},{0.f,0.f,0.f,0.f},{0.f,0.f,0.f,0.f}};

    // prologue: stage tile 0 -> buf 0
    #pragma unroll
    for (int i = 0; i < 4; ++i) gload16(pA[i], &As_u[0][(wave * 4 + i) * 256]);
    #pragma unroll
    for (int i = 0; i < 2; ++i) gload16(pB[i], &Bs_u[0][(wave * 2 + i) * 256]);
    #pragma unroll
    for (int i = 0; i < 4; ++i) pA[i] += BK;
    #pragma unroll
    for (int i = 0; i < 2; ++i) pB[i] += BK / 2;
    __syncthreads();

    int buf = 0;
    #pragma unroll 1
    for (int tt = 0; tt < NTb; ++tt) {
        if (tt + 1 < NTb) {
            #pragma unroll
            for (int i = 0; i < 4; ++i) gload16(pA[i], &As_u[buf ^ 1][(wave * 4 + i) * 256]);
            #pragma unroll
            for (int i = 0; i < 2; ++i) gload16(pB[i], &Bs_u[buf ^ 1][(wave * 2 + i) * 256]);
            #pragma unroll
            for (int i = 0; i < 4; ++i) pA[i] += BK;
            #pragma unroll
            for (int i = 0; i < 2; ++i) pB[i] += BK / 2;
        }
        const unsigned* Ab = As_u[buf];
        const unsigned* Bb = Bs_u[buf];
        #pragma unroll
        for (int kk = 0; kk < 2; ++kk) {
            int s0 = (kk * 8 + fr_hi * 2) ^ fr_lo;          // phys 16B slot of k-half 0
            f32x4 v0 = *(const f32x4*)&Ab[ar * 64 + s0 * 4];
            f32x4 v1 = *(const f32x4*)&Ab[ar * 64 + (s0 ^ 1) * 4];
            uint32x4 au = { cvt_pk(v0[0], v0[1]), cvt_pk(v0[2], v0[3]),
                            cvt_pk(v1[0], v1[1]), cvt_pk(v1[2], v1[3]) };
            bf16x8 a = __builtin_bit_cast(bf16x8, au);
            #pragma unroll
            for (int ct = 0; ct < 4; ++ct) {
                int bc   = ct * 16 + fr_lo;
                int boff = bc * 32 + (((kk * 4 + fr_hi) ^ (fr_lo & 7)) << 2);
                bf16x8 b = *(const bf16x8*)&Bb[boff];
                acc[ct] = __builtin_amdgcn_mfma_f32_16x16x32_bf16(a, b, acc[ct], 0, 0, 0);
            }
        }
        __syncthreads();
        buf ^= 1;
    }

    // C layout (m89): col = lane&15, row = (lane>>4)*4 + reg
    #pragma unroll
    for (int ct = 0; ct < 4; ++ct) {
        int c = ct * 16 + fr_lo;
        #pragma unroll
        for (int r = 0; r < 4; ++r) {
            int row = wave * 16 + fr_hi * 4 + r;
            atomicAdd(&hpre[(size_t)(row0 + row) * HID + c], acc[ct][r]);
        }
    }
}

// ---- layer-1 aggregation: one wave per edge, lane = column
__global__ void agg1_k(const int* __restrict__ ei, const float* __restrict__ w,
                       const float* __restrict__ dinv, const float* __restrict__ hpre,
                       float* __restrict__ agg1) {
    int e    = (blockIdx.x * 256 + threadIdx.x) >> 6;
    int lane = threadIdx.x & 63;
    int s = ei[e];
    int d = ei[N_EDGES + e];
    float wn = dinv[s] * w[e] * dinv[d];
    atomicAdd(&agg1[(size_t)d * HID + lane], wn * hpre[(size_t)s * HID + lane]);
}

// ---- finalize layer 1 (+ self loop + bias + relu) fused with h @ W2 -> s
__global__ void fin1_k(const float* __restrict__ agg1, const float* __restrict__ hpre,
                       const float* __restrict__ dinv, const float* __restrict__ b1,
                       const float* __restrict__ W2, float* __restrict__ s_out) {
    int i = (blockIdx.x * 256 + threadIdx.x) >> 6;
    int c = threadIdx.x & 63;
    float self = dinv[i] * dinv[i];
    float v = agg1[(size_t)i * HID + c] + self * hpre[(size_t)i * HID + c] + b1[c];
    v = fmaxf(v, 0.0f);
    float tv = v * W2[c];
    #pragma unroll
    for (int off = 32; off > 0; off >>= 1) tv += __shfl_xor(tv, off);
    if (c == 0) s_out[i] = tv;
}

// ---- layer-2 aggregation: scalar per edge
__global__ void agg2_k(const int* __restrict__ ei, const float* __restrict__ w,
                       const float* __restrict__ dinv, const float* __restrict__ s,
                       float* __restrict__ out_acc) {
    int e = blockIdx.x * 256 + threadIdx.x;
    int sr = ei[e];
    int d  = ei[N_EDGES + e];
    atomicAdd(&out_acc[d], dinv[sr] * w[e] * dinv[d] * s[sr]);
}

__global__ void fin2_k(const float* __restrict__ out_acc, const float* __restrict__ dinv,
                       const float* __restrict__ s, const float* __restrict__ b2,
                       float* __restrict__ out) {
    int i = blockIdx.x * 256 + threadIdx.x;
    out[i] = out_acc[i] + dinv[i] * dinv[i] * s[i] + b2[0];
}

extern "C" void kernel_launch(void* const* d_in, const int* in_sizes, int n_in,
                              void* d_out, int out_size, void* d_ws, size_t ws_size,
                              hipStream_t stream) {
    const float* x  = (const float*)d_in[0];
    const int*   ei = (const int*)d_in[1];      // int32 (harness delivers integers as int)
    const float* ew = (const float*)d_in[2];
    const float* W1 = (const float*)d_in[3];
    const float* b1 = (const float*)d_in[4];
    const float* W2 = (const float*)d_in[5];
    const float* b2 = (const float*)d_in[6];
    float* out = (float*)d_out;

    char* ws = (char*)d_ws;
    unsigned* w1t    = (unsigned*)(ws);                          // 2 MiB
    float*    hpre   = (float*)(ws + (2u << 20));                // 4 MiB
    float*    agg1   = (float*)(ws + (6u << 20));                // 4 MiB
    float*    outacc = (float*)(ws + (10u << 20));               // 64 KiB
    float*    deg    = (float*)(ws + (10u << 20) + (64u << 10)); // 64 KiB
    float*    dinv   = (float*)(ws + (10u << 20) + (128u << 10));
    float*    s      = (float*)(ws + (10u << 20) + (192u << 10));

    // zero hpre + agg1 + outacc + deg (contiguous region)
    hipMemsetAsync(ws + (2u << 20), 0, (8u << 20) + (128u << 10), stream);

    pack_w1t<<<(64 * (KDIM / 2)) / 256, 256, 0, stream>>>(W1, w1t);
    deg_acc<<<N_EDGES / 256, 256, 0, stream>>>(ei, ew, deg);
    dinv_k<<<N_NODES / 256, 256, 0, stream>>>(deg, dinv);
    gemm1<<<dim3(N_NODES / 64, 3), 256, 0, stream>>>(x, w1t, hpre);
    agg1_k<<<(N_EDGES * 64) / 256, 256, 0, stream>>>(ei, ew, dinv, hpre, agg1);
    fin1_k<<<N_NODES / 4, 256, 0, stream>>>(agg1, hpre, dinv, b1, W2, s);
    agg2_k<<<N_EDGES / 256, 256, 0, stream>>>(ei, ew, dinv, s, outacc);
    fin2_k<<<N_NODES / 256, 256, 0, stream>>>(outacc, dinv, s, b2, out);
}